// Round 8
// baseline (118.984 us; speedup 1.0000x reference)
//
#include <hip/hip_runtime.h>
#include <hip/hip_bf16.h>

// TopologicalMap SOM: x (8192,64) f32, w (64,16384) f32,
// out (8192,16384) f32 = x2[b] + w2[n] - 2 * (x @ w)[b,n]
#define BATCH 8192
#define IN_D  64
#define OUT_N 16384

typedef __attribute__((ext_vector_type(8)))  short bf16x8;   // 8 bf16 = 4 VGPRs
typedef __attribute__((ext_vector_type(16))) float f32x16;   // 32x32 MFMA acc
typedef __attribute__((ext_vector_type(4)))  float f32x4;

// d_ws layout (~3.1 MB), gated on ws_size with a no-ws fallback:
static constexpr size_t WT_OFF  = 0;                                   // wT bf16 [N][64]
static constexpr size_t XB_OFF  = WT_OFF + (size_t)OUT_N * IN_D * 2;   // xb bf16 [B][64]
static constexpr size_t X2_OFF  = XB_OFF + (size_t)BATCH * IN_D * 2;   // x2 f32 [B]
static constexpr size_t W2_OFF  = X2_OFF + (size_t)BATCH * 4;          // w2 f32 [N]
static constexpr size_t WS_NEED = W2_OFF + (size_t)OUT_N * 4;

// ---- fused prepass: blocks [0,512) convert x, blocks [512,768) convert w ----
__global__ void prep_all(const float* __restrict__ x, const float* __restrict__ w,
                         __hip_bfloat16* __restrict__ xb, float* __restrict__ x2,
                         __hip_bfloat16* __restrict__ wt, float* __restrict__ w2) {
    const int t = threadIdx.x;
    if (blockIdx.x < 512) {
        // x -> bf16 rows + x2 row sums (fp32 exact). 16 rows/block, 16 lanes/row.
        const int row = blockIdx.x * 16 + (t >> 4);
        const int kq  = t & 15;
        const f32x4 v = *reinterpret_cast<const f32x4*>(x + (size_t)row * IN_D + kq * 4);
        float s = v[0]*v[0] + v[1]*v[1] + v[2]*v[2] + v[3]*v[3];
        s += __shfl_xor(s, 1);
        s += __shfl_xor(s, 2);
        s += __shfl_xor(s, 4);
        s += __shfl_xor(s, 8);
        if (kq == 0) x2[row] = s;
        union { __hip_bfloat16 h[4]; ushort4 u; } cvt;
        cvt.h[0] = __float2bfloat16(v[0]);
        cvt.h[1] = __float2bfloat16(v[1]);
        cvt.h[2] = __float2bfloat16(v[2]);
        cvt.h[3] = __float2bfloat16(v[3]);
        *reinterpret_cast<ushort4*>(&xb[(size_t)row * IN_D + kq * 4]) = cvt.u;
    } else {
        // w -> bf16 transposed [N][64] + w2 col sums. 64 cols/block.
        __shared__ float tile[64][65];
        const int n0 = (blockIdx.x - 512) * 64;
        #pragma unroll
        for (int i = 0; i < 4; ++i) {
            int p = i * 256 + t;                  // 0..1023 float4 slots
            int d = p >> 4, nq = p & 15;
            const f32x4 v = *reinterpret_cast<const f32x4*>(w + (size_t)d * OUT_N + n0 + nq * 4);
            tile[d][nq*4+0] = v[0]; tile[d][nq*4+1] = v[1];
            tile[d][nq*4+2] = v[2]; tile[d][nq*4+3] = v[3];
        }
        __syncthreads();
        if (t < 64) {
            float s = 0.f;
            #pragma unroll
            for (int d = 0; d < 64; ++d) { float f = tile[d][t]; s += f * f; }
            w2[n0 + t] = s;
        }
        #pragma unroll
        for (int i = 0; i < 4; ++i) {
            int c = i * 256 + t;                  // chunks of 4 bf16
            int n = c >> 4, kq = c & 15;
            union { __hip_bfloat16 h[4]; ushort4 u; } cvt;
            #pragma unroll
            for (int j = 0; j < 4; ++j) cvt.h[j] = __float2bfloat16(tile[kq*4+j][n]);
            *reinterpret_cast<ushort4*>(&wt[(size_t)(n0 + n) * IN_D + kq * 4]) = cvt.u;
        }
    }
}

// ---- main GEMM: 128x256 block, 8 waves (2m x 4n), wave tile 64x64. ---------
// Epilogue: block-wide 128KB LDS transpose (one barrier), then each wave
// stores full 1KB-contiguous block-rows via NT dwordx4 — exactly the
// fillBuffer wave pattern (6.7 TB/s reference).
__global__ __launch_bounds__(512, 1) void som_gemm(
    const __hip_bfloat16* __restrict__ xb, const __hip_bfloat16* __restrict__ wt,
    const float* __restrict__ x2, const float* __restrict__ w2,
    float* __restrict__ out) {
    __shared__ float tile[128][256];              // 128 KB (<=160KB/CU, 1 blk/CU)

    // bijective swizzle: 4096 blocks = 8 XCDs x 512
    const int bid = blockIdx.x;
    const int swz = (bid & 7) * 512 + (bid >> 3);
    const int bx  = swz & 63;    // n-tile (256 wide)
    const int by  = swz >> 6;    // m-tile (128 tall)

    const int lane = threadIdx.x & 63;
    const int wv   = threadIdx.x >> 6;            // 0..7
    const int wr   = wv >> 2, wc = wv & 3;
    const int m0   = by * 128 + wr * 64;          // wave: 64 rows
    const int n0   = bx * 256 + wc * 64;          // wave: 64 cols
    const int l31  = lane & 31, l5 = lane >> 5;

    // A: lane -> xb[m0+mi*32+l31][ks*16 + l5*8 ..+7]; B likewise (16B loads)
    bf16x8 a[2][4], b[2][4];
    #pragma unroll
    for (int mi = 0; mi < 2; ++mi) {
        const __hip_bfloat16* base = xb + (size_t)(m0 + mi * 32 + l31) * IN_D + l5 * 8;
        #pragma unroll
        for (int ks = 0; ks < 4; ++ks)
            a[mi][ks] = *reinterpret_cast<const bf16x8*>(base + ks * 16);
    }
    #pragma unroll
    for (int ni = 0; ni < 2; ++ni) {
        const __hip_bfloat16* base = wt + (size_t)(n0 + ni * 32 + l31) * IN_D + l5 * 8;
        #pragma unroll
        for (int ks = 0; ks < 4; ++ks)
            b[ni][ks] = *reinterpret_cast<const bf16x8*>(base + ks * 16);
    }

    // Epilogue operands for the read-back phase (L2-resident, prefetched).
    const f32x4 w2q = *reinterpret_cast<const f32x4*>(w2 + bx * 256 + lane * 4);

    f32x16 acc[2][2] = {};
    #pragma unroll
    for (int ks = 0; ks < 4; ++ks)
        #pragma unroll
        for (int mi = 0; mi < 2; ++mi)
            #pragma unroll
            for (int ni = 0; ni < 2; ++ni)
                acc[mi][ni] = __builtin_amdgcn_mfma_f32_32x32x16_bf16(
                    a[mi][ks], b[ni][ks], acc[mi][ni], 0, 0, 0);

    // Scatter acc into block-wide LDS at its C layout (m74/m101):
    // row_loc = wr*64 + mi*32 + (reg&3)+8*(reg>>2)+4*l5, col_loc = wc*64+ni*32+l31.
    // Bank = col&31 = l31 -> 2-way alias across l5 halves = free.
    #pragma unroll
    for (int mi = 0; mi < 2; ++mi)
        #pragma unroll
        for (int ni = 0; ni < 2; ++ni)
            #pragma unroll
            for (int rg = 0; rg < 4; ++rg)
                #pragma unroll
                for (int j = 0; j < 4; ++j)
                    tile[wr * 64 + mi * 32 + j + 8 * rg + 4 * l5]
                        [wc * 64 + ni * 32 + l31] = acc[mi][ni][rg * 4 + j];

    __syncthreads();

    // Read back: wave wv handles rows {wv, wv+8, ...}; one ds_read_b128 sweep
    // + one NT dwordx4 store covers a full 1KB-contiguous output row segment.
    #pragma unroll
    for (int i = 0; i < 16; ++i) {
        const int rloc = i * 8 + wv;
        const int row  = by * 128 + rloc;
        const f32x4 v  = *reinterpret_cast<const f32x4*>(&tile[rloc][lane * 4]);
        const float x2v = x2[row];
        f32x4 o;
        o[0] = x2v + w2q[0] - 2.0f * v[0];
        o[1] = x2v + w2q[1] - 2.0f * v[1];
        o[2] = x2v + w2q[2] - 2.0f * v[2];
        o[3] = x2v + w2q[3] - 2.0f * v[3];
        __builtin_nontemporal_store(o,
            reinterpret_cast<f32x4*>(out + (size_t)row * OUT_N + bx * 256 + lane * 4));
    }
}

// ---- fallback if ws_size is too small (no scratch used) --------------------
__global__ void som_fallback(const float* __restrict__ x, const float* __restrict__ w,
                             float* __restrict__ out) {
    __shared__ float xs[16][64];
    const int t  = threadIdx.x;
    const int m0 = blockIdx.y * 16;
    const int n0 = blockIdx.x * 256;
    {
        int row = t >> 4, kq = t & 15;
        const f32x4 v = *reinterpret_cast<const f32x4*>(x + (size_t)(m0 + row) * IN_D + kq * 4);
        xs[row][kq*4+0] = v[0]; xs[row][kq*4+1] = v[1];
        xs[row][kq*4+2] = v[2]; xs[row][kq*4+3] = v[3];
    }
    __syncthreads();
    const int col = n0 + t;
    float acc[16];
    #pragma unroll
    for (int r = 0; r < 16; ++r) acc[r] = 0.f;
    for (int d = 0; d < 64; ++d) {
        const float wv = w[(size_t)d * OUT_N + col];
        #pragma unroll
        for (int r = 0; r < 16; ++r) { float df = xs[r][d] - wv; acc[r] += df * df; }
    }
    #pragma unroll
    for (int r = 0; r < 16; ++r)
        out[(size_t)(m0 + r) * OUT_N + col] = acc[r];
}

extern "C" void kernel_launch(void* const* d_in, const int* in_sizes, int n_in,
                              void* d_out, int out_size, void* d_ws, size_t ws_size,
                              hipStream_t stream) {
    const float* x = (const float*)d_in[0];   // (8192, 64)
    const float* w = (const float*)d_in[1];   // (64, 16384)
    float* out = (float*)d_out;               // (8192, 16384)

    if (ws_size >= WS_NEED) {
        char* ws = (char*)d_ws;
        __hip_bfloat16* wt = (__hip_bfloat16*)(ws + WT_OFF);
        __hip_bfloat16* xb = (__hip_bfloat16*)(ws + XB_OFF);
        float* x2 = (float*)(ws + X2_OFF);
        float* w2 = (float*)(ws + W2_OFF);
        prep_all<<<512 + 256, 256, 0, stream>>>(x, w, xb, x2, wt, w2);
        som_gemm<<<4096, 512, 0, stream>>>(xb, wt, x2, w2, out);
    } else {
        dim3 grid(OUT_N / 256, BATCH / 16);
        som_fallback<<<grid, 256, 0, stream>>>(x, w, out);
    }
}

// Round 9
// 105.623 us; speedup vs baseline: 1.1265x; 1.1265x over previous
//
#include <hip/hip_runtime.h>
#include <hip/hip_bf16.h>

// TopologicalMap SOM: x (8192,64) f32, w (64,16384) f32,
// out (8192,16384) f32 = x2[b] + w2[n] - 2 * (x @ w)[b,n]
#define BATCH 8192
#define IN_D  64
#define OUT_N 16384

typedef __attribute__((ext_vector_type(8)))  short bf16x8;   // 8 bf16 = 4 VGPRs
typedef __attribute__((ext_vector_type(16))) float f32x16;   // 32x32 MFMA acc
typedef __attribute__((ext_vector_type(4)))  float f32x4;

// d_ws layout (~3.1 MB), gated on ws_size with a no-ws fallback:
static constexpr size_t WT_OFF  = 0;                                   // wT bf16 [N][64]
static constexpr size_t XB_OFF  = WT_OFF + (size_t)OUT_N * IN_D * 2;   // xb bf16 [B][64]
static constexpr size_t X2_OFF  = XB_OFF + (size_t)BATCH * IN_D * 2;   // x2 f32 [B]
static constexpr size_t W2_OFF  = X2_OFF + (size_t)BATCH * 4;          // w2 f32 [N]
static constexpr size_t WS_NEED = W2_OFF + (size_t)OUT_N * 4;

// ---- fused prepass: blocks [0,512) convert x, blocks [512,768) convert w ----
__global__ void prep_all(const float* __restrict__ x, const float* __restrict__ w,
                         __hip_bfloat16* __restrict__ xb, float* __restrict__ x2,
                         __hip_bfloat16* __restrict__ wt, float* __restrict__ w2) {
    const int t = threadIdx.x;
    if (blockIdx.x < 512) {
        // x -> bf16 rows + x2 row sums (fp32 exact). 16 rows/block, 16 lanes/row.
        const int row = blockIdx.x * 16 + (t >> 4);
        const int kq  = t & 15;
        const f32x4 v = *reinterpret_cast<const f32x4*>(x + (size_t)row * IN_D + kq * 4);
        float s = v[0]*v[0] + v[1]*v[1] + v[2]*v[2] + v[3]*v[3];
        s += __shfl_xor(s, 1);
        s += __shfl_xor(s, 2);
        s += __shfl_xor(s, 4);
        s += __shfl_xor(s, 8);
        if (kq == 0) x2[row] = s;
        union { __hip_bfloat16 h[4]; ushort4 u; } cvt;
        cvt.h[0] = __float2bfloat16(v[0]);
        cvt.h[1] = __float2bfloat16(v[1]);
        cvt.h[2] = __float2bfloat16(v[2]);
        cvt.h[3] = __float2bfloat16(v[3]);
        *reinterpret_cast<ushort4*>(&xb[(size_t)row * IN_D + kq * 4]) = cvt.u;
    } else {
        // w -> bf16 transposed [N][64] + w2 col sums. 64 cols/block.
        __shared__ float tile[64][65];
        const int n0 = (blockIdx.x - 512) * 64;
        #pragma unroll
        for (int i = 0; i < 4; ++i) {
            int p = i * 256 + t;                  // 0..1023 float4 slots
            int d = p >> 4, nq = p & 15;
            const f32x4 v = *reinterpret_cast<const f32x4*>(w + (size_t)d * OUT_N + n0 + nq * 4);
            tile[d][nq*4+0] = v[0]; tile[d][nq*4+1] = v[1];
            tile[d][nq*4+2] = v[2]; tile[d][nq*4+3] = v[3];
        }
        __syncthreads();
        if (t < 64) {
            float s = 0.f;
            #pragma unroll
            for (int d = 0; d < 64; ++d) { float f = tile[d][t]; s += f * f; }
            w2[n0 + t] = s;
        }
        #pragma unroll
        for (int i = 0; i < 4; ++i) {
            int c = i * 256 + t;                  // chunks of 4 bf16
            int n = c >> 4, kq = c & 15;
            union { __hip_bfloat16 h[4]; ushort4 u; } cvt;
            #pragma unroll
            for (int j = 0; j < 4; ++j) cvt.h[j] = __float2bfloat16(tile[kq*4+j][n]);
            *reinterpret_cast<ushort4*>(&wt[(size_t)(n0 + n) * IN_D + kq * 4]) = cvt.u;
        }
    }
}

// ---- main GEMM: R7 structure + register-lean K-loop for 2-blocks/CU --------
// 128x256 block, 8 waves (2m x 4n), wave tile 64x64. Operand frags loaded
// per-ks (live regs ~16 instead of 64) + __launch_bounds__(512,4) => VGPR<=128
// => 4 waves/SIMD => 2 blocks/CU co-resident (LDS 64KB x2 <= 160KB). Barrier-
// free epilogue: per-wave LDS slice transpose -> NT dwordx4 (R7's proven
// pattern); a fresh block's load/MFMA phase overlaps the old block's drain.
__global__ __launch_bounds__(512, 4) void som_gemm(
    const __hip_bfloat16* __restrict__ xb, const __hip_bfloat16* __restrict__ wt,
    const float* __restrict__ x2, const float* __restrict__ w2,
    float* __restrict__ out) {
    __shared__ float lds[8][32][64];              // 8 waves x 8KB = 64KB

    // bijective swizzle: 4096 blocks = 8 XCDs x 512
    const int bid = blockIdx.x;
    const int swz = (bid & 7) * 512 + (bid >> 3);
    const int bx  = swz & 63;    // n-tile (256 wide)
    const int by  = swz >> 6;    // m-tile (128 tall)

    const int lane = threadIdx.x & 63;
    const int wv   = threadIdx.x >> 6;            // 0..7
    const int m0   = by * 128 + (wv >> 2) * 64;   // wave: 64 rows
    const int n0   = bx * 256 + (wv & 3) * 64;    // wave: 64 cols
    const int l31  = lane & 31, l5 = lane >> 5;

    const __hip_bfloat16* a0p = xb + (size_t)(m0 + l31) * IN_D + l5 * 8;
    const __hip_bfloat16* a1p = a0p + (size_t)32 * IN_D;
    const __hip_bfloat16* b0p = wt + (size_t)(n0 + l31) * IN_D + l5 * 8;
    const __hip_bfloat16* b1p = b0p + (size_t)32 * IN_D;

    // Epilogue operands (L2-resident) prefetched before the MFMA phase.
    const int rrow = lane >> 4;   // 0..3
    const int colq = lane & 15;   // float4 column index within the 64-col tile
    const f32x4 w2q = *reinterpret_cast<const f32x4*>(w2 + n0 + colq * 4);

    f32x16 acc[2][2] = {};
    #pragma unroll
    for (int ks = 0; ks < 4; ++ks) {
        const bf16x8 a0 = *reinterpret_cast<const bf16x8*>(a0p + ks * 16);
        const bf16x8 a1 = *reinterpret_cast<const bf16x8*>(a1p + ks * 16);
        const bf16x8 b0 = *reinterpret_cast<const bf16x8*>(b0p + ks * 16);
        const bf16x8 b1 = *reinterpret_cast<const bf16x8*>(b1p + ks * 16);
        acc[0][0] = __builtin_amdgcn_mfma_f32_32x32x16_bf16(a0, b0, acc[0][0], 0, 0, 0);
        acc[0][1] = __builtin_amdgcn_mfma_f32_32x32x16_bf16(a0, b1, acc[0][1], 0, 0, 0);
        acc[1][0] = __builtin_amdgcn_mfma_f32_32x32x16_bf16(a1, b0, acc[1][0], 0, 0, 0);
        acc[1][1] = __builtin_amdgcn_mfma_f32_32x32x16_bf16(a1, b1, acc[1][1], 0, 0, 0);
    }

    // Epilogue per mi: scatter acc (C layout m74/m101: row_loc =
    // (reg&3)+8*(reg>>2)+4*l5, col_loc = ni*32+l31) into the wave's LDS
    // slice, read back row-major float4, NT dwordx4 store. Same-wave RAW
    // only -> no barrier (compiler orders via lgkmcnt).
    #pragma unroll
    for (int mi = 0; mi < 2; ++mi) {
        #pragma unroll
        for (int ni = 0; ni < 2; ++ni)
            #pragma unroll
            for (int rg = 0; rg < 4; ++rg)
                #pragma unroll
                for (int j = 0; j < 4; ++j)
                    lds[wv][j + 8 * rg + 4 * l5][ni * 32 + l31] = acc[mi][ni][rg * 4 + j];

        #pragma unroll
        for (int i = 0; i < 8; ++i) {
            const int rloc = i * 4 + rrow;
            const int row  = m0 + mi * 32 + rloc;
            const f32x4 v  = *reinterpret_cast<const f32x4*>(&lds[wv][rloc][colq * 4]);
            const float x2v = x2[row];
            f32x4 o;
            o[0] = x2v + w2q[0] - 2.0f * v[0];
            o[1] = x2v + w2q[1] - 2.0f * v[1];
            o[2] = x2v + w2q[2] - 2.0f * v[2];
            o[3] = x2v + w2q[3] - 2.0f * v[3];
            __builtin_nontemporal_store(o,
                reinterpret_cast<f32x4*>(out + (size_t)row * OUT_N + n0 + colq * 4));
        }
    }
}

// ---- fallback if ws_size is too small (no scratch used) --------------------
__global__ void som_fallback(const float* __restrict__ x, const float* __restrict__ w,
                             float* __restrict__ out) {
    __shared__ float xs[16][64];
    const int t  = threadIdx.x;
    const int m0 = blockIdx.y * 16;
    const int n0 = blockIdx.x * 256;
    {
        int row = t >> 4, kq = t & 15;
        const f32x4 v = *reinterpret_cast<const f32x4*>(x + (size_t)(m0 + row) * IN_D + kq * 4);
        xs[row][kq*4+0] = v[0]; xs[row][kq*4+1] = v[1];
        xs[row][kq*4+2] = v[2]; xs[row][kq*4+3] = v[3];
    }
    __syncthreads();
    const int col = n0 + t;
    float acc[16];
    #pragma unroll
    for (int r = 0; r < 16; ++r) acc[r] = 0.f;
    for (int d = 0; d < 64; ++d) {
        const float wv = w[(size_t)d * OUT_N + col];
        #pragma unroll
        for (int r = 0; r < 16; ++r) { float df = xs[r][d] - wv; acc[r] += df * df; }
    }
    #pragma unroll
    for (int r = 0; r < 16; ++r)
        out[(size_t)(m0 + r) * OUT_N + col] = acc[r];
}

extern "C" void kernel_launch(void* const* d_in, const int* in_sizes, int n_in,
                              void* d_out, int out_size, void* d_ws, size_t ws_size,
                              hipStream_t stream) {
    const float* x = (const float*)d_in[0];   // (8192, 64)
    const float* w = (const float*)d_in[1];   // (64, 16384)
    float* out = (float*)d_out;               // (8192, 16384)

    if (ws_size >= WS_NEED) {
        char* ws = (char*)d_ws;
        __hip_bfloat16* wt = (__hip_bfloat16*)(ws + WT_OFF);
        __hip_bfloat16* xb = (__hip_bfloat16*)(ws + XB_OFF);
        float* x2 = (float*)(ws + X2_OFF);
        float* w2 = (float*)(ws + W2_OFF);
        prep_all<<<512 + 256, 256, 0, stream>>>(x, w, xb, x2, wt, w2);
        som_gemm<<<4096, 512, 0, stream>>>(xb, wt, x2, w2, out);
    } else {
        dim3 grid(OUT_N / 256, BATCH / 16);
        som_fallback<<<grid, 256, 0, stream>>>(x, w, out);
    }
}